// Round 4
// baseline (179.492 us; speedup 1.0000x reference)
//
#include <hip/hip_runtime.h>

typedef __attribute__((ext_vector_type(8))) __bf16 bf16x8;
typedef __attribute__((ext_vector_type(4))) float f32x4;
typedef unsigned int uint32;

#define HW   4096
#define CCH  64
#define DQ   32
#define OC   32
#define LOG2E 1.4426950408889634f

// Workspace layout (float offsets). Total 6,031,360 floats = 24.1 MB.
#define WSV_OFF  0u                       // 32*64 f32
#define QB_OFF   2048u                    // bf16 [b][n][32] (pre-scaled log2e)
#define KB_OFF   (QB_OFF + 524288u)       // bf16 [b][m][32]
#define XS_OFF   (KB_OFF + 524288u)       // f32  [b][o][n]
#define V2_OFF   (XS_OFF + 1048576u)      // f32  [b][o][m]
#define ZP_OFF   (V2_OFF + 1048576u)      // f32  [8][b][m] partial Z
#define VZB_OFF  (ZP_OFF + 262144u)       // bf16 [b][o][m]
#define OUTP_OFF (VZB_OFF + 524288u)      // bf16 [8][b][o][n] partial out

__device__ __forceinline__ uint32 f2bf(float x) {   // RNE
    uint32 u = __builtin_bit_cast(uint32, x);
    return (u + 0x7fffu + ((u >> 16) & 1u)) >> 16;
}
__device__ __forceinline__ uint32 packbf(float a, float b) {
    return f2bf(a) | (f2bf(b) << 16);
}
// 1-op truncating pack: dst = {hi16(b), hi16(a)} via v_perm_b32
__device__ __forceinline__ uint32 packbf_t(float a, float b) {
    return __builtin_amdgcn_perm(__builtin_bit_cast(uint32, b),
                                 __builtin_bit_cast(uint32, a), 0x07060302u);
}
__device__ __forceinline__ bf16x8 ldfrag(const unsigned short* p) {
    union { uint4 u; bf16x8 f; } t;
    t.u = *(const uint4*)p;
    return t.f;
}
__device__ __forceinline__ float fexp2(float x) {
#if __has_builtin(__builtin_amdgcn_exp2f)
    return __builtin_amdgcn_exp2f(x);
#else
    return __expf(x * 0.6931471805599453f);
#endif
}

// ---------------------------------------------------------------------------
// Kernel 0: Wsv = Wsc @ Wv
__global__ __launch_bounds__(256) void k_wcomb(const float* __restrict__ Wsc,
                                               const float* __restrict__ Wv,
                                               float* __restrict__ Wsv) {
    int t = blockIdx.x * 256 + threadIdx.x;
    if (t < OC * CCH) {
        int o = t / CCH, ci = t % CCH;
        float s = 0.f;
        #pragma unroll
        for (int c = 0; c < CCH; ++c) s += Wsc[o * CCH + c] * Wv[c * CCH + ci];
        Wsv[t] = s;
    }
}

// ---------------------------------------------------------------------------
// Kernel 1: projections. W via wave-uniform scalar loads (no LDS).
// 512 blocks x 256; block = 64 pixels; wave g: 0=q,1=k,2=v2,3=xs.
__global__ __launch_bounds__(256) void k_proj(
    const float* __restrict__ x1, const float* __restrict__ x2,
    const float* __restrict__ Wq, const float* __restrict__ bq,
    const float* __restrict__ Wk, const float* __restrict__ bk,
    const float* __restrict__ Wsv, const float* __restrict__ Wsc,
    unsigned short* __restrict__ qb, unsigned short* __restrict__ kb,
    float* __restrict__ v2, float* __restrict__ xs) {
    int t = threadIdx.x;
    int g = __builtin_amdgcn_readfirstlane(t >> 6);   // wave-uniform
    int l = t & 63;
    int p = blockIdx.x * 64 + l;
    int b = p >> 12, n = p & 4095;
    const float* x1b = x1 + (size_t)b * 32 * HW + n;
    const float* x2b = x2 + (size_t)b * 32 * HW + n;
    float x[CCH];
    #pragma unroll
    for (int c = 0; c < 32; ++c) x[c] = x1b[(size_t)c * HW];
    #pragma unroll
    for (int c = 0; c < 32; ++c) x[32 + c] = x2b[(size_t)c * HW];

    if (g < 2) {
        const float* W    = g ? Wk : Wq;
        const float* bias = g ? bk : bq;
        float scale = g ? 1.0f : LOG2E;
        unsigned short* dst = g ? kb : qb;
        size_t row = ((size_t)b * HW + n) * DQ;
        for (int d0 = 0; d0 < DQ; d0 += 8) {
            float r[8];
            #pragma unroll
            for (int i = 0; i < 8; ++i) {
                const float* wr = W + (d0 + i) * CCH;
                float a = bias[d0 + i];
                #pragma unroll
                for (int c = 0; c < CCH; ++c) a += wr[c] * x[c];
                r[i] = a * scale;
            }
            uint4 u;
            u.x = packbf(r[0], r[1]); u.y = packbf(r[2], r[3]);
            u.z = packbf(r[4], r[5]); u.w = packbf(r[6], r[7]);
            *(uint4*)(dst + row + d0) = u;
        }
    } else {
        const float* W = (g == 2) ? Wsv : Wsc;
        float* dst     = (g == 2) ? v2  : xs;
        for (int o = 0; o < OC; ++o) {
            const float* wr = W + o * CCH;
            float a = 0.f;
            #pragma unroll
            for (int c = 0; c < CCH; ++c) a += wr[c] * x[c];
            dst[((size_t)b * OC + o) * HW + n] = a;
        }
    }
}

// ---------------------------------------------------------------------------
// Kernel 2: partial Zp[nc][b][m] = sum_{n in 512-chunk} exp2(q_n . k_m)
// grid = 2048: b = bid&7 (XCD-pinned), nc = (bid>>3)&7, mg = bid>>6.
__global__ __launch_bounds__(256, 8) void k_stats(
    const unsigned short* __restrict__ kb, const unsigned short* __restrict__ qb,
    float* __restrict__ zp) {
    int t = threadIdx.x;
    int w = t >> 6, l = t & 63;
    int lr = l & 15, lq = l >> 4;
    int bid = blockIdx.x;
    int b = bid & 7, nc = (bid >> 3) & 7, mg = bid >> 6;   // mg 0..31
    int m0 = mg * 128 + w * 32;

    const unsigned short* kbb = kb + ((size_t)b * HW) * DQ;
    bf16x8 af0 = ldfrag(kbb + (size_t)(m0 + lr) * DQ + lq * 8);
    bf16x8 af1 = ldfrag(kbb + (size_t)(m0 + 16 + lr) * DQ + lq * 8);
    const unsigned short* qp = qb + ((size_t)b * HW + nc * 512 + lr) * DQ + lq * 8;

    f32x4 acc0 = {0.f, 0.f, 0.f, 0.f};
    f32x4 acc1 = {0.f, 0.f, 0.f, 0.f};
    f32x4 zz = {0.f, 0.f, 0.f, 0.f};
    #pragma unroll 4
    for (int i = 0; i < 32; ++i) {
        bf16x8 qf = ldfrag(qp);
        qp += 16 * DQ;
        f32x4 s0 = __builtin_amdgcn_mfma_f32_16x16x32_bf16(af0, qf, zz, 0, 0, 0);
        f32x4 s1 = __builtin_amdgcn_mfma_f32_16x16x32_bf16(af1, qf, zz, 0, 0, 0);
        acc0.x += fexp2(s0.x); acc0.y += fexp2(s0.y);
        acc0.z += fexp2(s0.z); acc0.w += fexp2(s0.w);
        acc1.x += fexp2(s1.x); acc1.y += fexp2(s1.y);
        acc1.z += fexp2(s1.z); acc1.w += fexp2(s1.w);
    }
    #pragma unroll
    for (int off = 1; off < 16; off <<= 1) {
        acc0.x += __shfl_xor(acc0.x, off); acc0.y += __shfl_xor(acc0.y, off);
        acc0.z += __shfl_xor(acc0.z, off); acc0.w += __shfl_xor(acc0.w, off);
        acc1.x += __shfl_xor(acc1.x, off); acc1.y += __shfl_xor(acc1.y, off);
        acc1.z += __shfl_xor(acc1.z, off); acc1.w += __shfl_xor(acc1.w, off);
    }
    if (lr == 0) {
        size_t base = (size_t)nc * 32768 + (size_t)b * HW;
        zp[base + m0 + lq * 4 + 0] = acc0.x;
        zp[base + m0 + lq * 4 + 1] = acc0.y;
        zp[base + m0 + lq * 4 + 2] = acc0.z;
        zp[base + m0 + lq * 4 + 3] = acc0.w;
        zp[base + m0 + 16 + lq * 4 + 0] = acc1.x;
        zp[base + m0 + 16 + lq * 4 + 1] = acc1.y;
        zp[base + m0 + 16 + lq * 4 + 2] = acc1.z;
        zp[base + m0 + 16 + lq * 4 + 3] = acc1.w;
    }
}

// ---------------------------------------------------------------------------
// Kernel 3 (fused scale+vz): zs = gamma/sum(zp); vzb[b][o][m] = bf16(v2*zs)
// grid 128 blocks; thread = one (b, m).
__global__ __launch_bounds__(256) void k_zvz(const float* __restrict__ zp,
                                             const float* __restrict__ v2,
                                             const float* __restrict__ gamma,
                                             unsigned short* __restrict__ vzb) {
    int i = blockIdx.x * 256 + threadIdx.x;   // 32768 = [b][m]
    float s = 0.f;
    #pragma unroll
    for (int nc = 0; nc < 8; ++nc) s += zp[nc * 32768 + i];
    float zs = gamma[0] / s;
    int b = i >> 12, m = i & 4095;
    const float* vsrc = v2 + ((size_t)b * OC) * HW + m;
    unsigned short* dst = vzb + ((size_t)b * OC) * HW + m;
    #pragma unroll 8
    for (int o = 0; o < OC; ++o) {
        dst[(size_t)o * HW] = (unsigned short)f2bf(vsrc[(size_t)o * HW] * zs);
    }
}

// ---------------------------------------------------------------------------
// Kernel 4: partial outp[mc][b][o][n] (bf16) = sum_{m in 512-chunk} vzb*exp2(q.k)
// grid = 2048: b = bid&7 (XCD-pinned), mc = (bid>>3)&7, ng = bid>>6 (0..31).
__global__ __launch_bounds__(256, 8) void k_attn(
    const unsigned short* __restrict__ qb, const unsigned short* __restrict__ kb,
    const unsigned short* __restrict__ vzb, unsigned short* __restrict__ outp) {
    __shared__ unsigned short fb[8192];   // 16 KB: 4 waves * 2 tiles * 2 ph * 512
    int t = threadIdx.x;
    int w = t >> 6, l = t & 63;
    int lr = l & 15, lq = l >> 4;
    int bid = blockIdx.x;
    int b = bid & 7, mc = (bid >> 3) & 7, ng = bid >> 6;
    int nA = ng * 128 + w * 32;

    unsigned short* fbw = fb + w * 2048;
    int aw = (lr + ((lq >> 1) << 4)) * 8 + (lq & 1) * 4;

    bf16x8 qfA = ldfrag(qb + ((size_t)b * HW + nA + lr) * DQ + lq * 8);
    bf16x8 qfB = ldfrag(qb + ((size_t)b * HW + nA + 16 + lr) * DQ + lq * 8);
    const unsigned short* kp = kb + ((size_t)b * HW + lr) * DQ + lq * 8;
    const unsigned short* vp = vzb + ((size_t)b * OC + lr) * HW + lq * 8;

    f32x4 accA0 = {0.f,0.f,0.f,0.f}, accA1 = {0.f,0.f,0.f,0.f};
    f32x4 accB0 = {0.f,0.f,0.f,0.f}, accB1 = {0.f,0.f,0.f,0.f};
    f32x4 zz = {0.f,0.f,0.f,0.f};

    int mbeg = mc * 512;
    for (int m0 = mbeg; m0 < mbeg + 512; m0 += 64) {
        #pragma unroll
        for (int ph = 0; ph < 2; ++ph) {
            int mb = m0 + ph * 32;
            unsigned short* fA = fbw + ph * 512;
            unsigned short* fB = fbw + 1024 + ph * 512;
            bf16x8 a0  = ldfrag(kp + (size_t)mb * DQ);
            bf16x8 a1  = ldfrag(kp + (size_t)(mb + 16) * DQ);
            bf16x8 va0 = ldfrag(vp + mb);
            bf16x8 va1 = ldfrag(vp + 16 * HW + mb);
            f32x4 sA0 = __builtin_amdgcn_mfma_f32_16x16x32_bf16(a0, qfA, zz, 0, 0, 0);
            f32x4 sA1 = __builtin_amdgcn_mfma_f32_16x16x32_bf16(a1, qfA, zz, 0, 0, 0);
            f32x4 sB0 = __builtin_amdgcn_mfma_f32_16x16x32_bf16(a0, qfB, zz, 0, 0, 0);
            f32x4 sB1 = __builtin_amdgcn_mfma_f32_16x16x32_bf16(a1, qfB, zz, 0, 0, 0);
            uint2 pA0, pA1, pB0, pB1;
            pA0.x = packbf_t(fexp2(sA0.x), fexp2(sA0.y));
            pA0.y = packbf_t(fexp2(sA0.z), fexp2(sA0.w));
            pA1.x = packbf_t(fexp2(sA1.x), fexp2(sA1.y));
            pA1.y = packbf_t(fexp2(sA1.z), fexp2(sA1.w));
            pB0.x = packbf_t(fexp2(sB0.x), fexp2(sB0.y));
            pB0.y = packbf_t(fexp2(sB0.z), fexp2(sB0.w));
            pB1.x = packbf_t(fexp2(sB1.x), fexp2(sB1.y));
            pB1.y = packbf_t(fexp2(sB1.z), fexp2(sB1.w));
            *(uint2*)(fA + aw)       = pA0;
            *(uint2*)(fA + aw + 256) = pA1;
            *(uint2*)(fB + aw)       = pB0;
            *(uint2*)(fB + aw + 256) = pB1;
            bf16x8 pfA = ldfrag(fA + l * 8);
            bf16x8 pfB = ldfrag(fB + l * 8);
            accA0 = __builtin_amdgcn_mfma_f32_16x16x32_bf16(va0, pfA, accA0, 0, 0, 0);
            accA1 = __builtin_amdgcn_mfma_f32_16x16x32_bf16(va1, pfA, accA1, 0, 0, 0);
            accB0 = __builtin_amdgcn_mfma_f32_16x16x32_bf16(va0, pfB, accB0, 0, 0, 0);
            accB1 = __builtin_amdgcn_mfma_f32_16x16x32_bf16(va1, pfB, accB1, 0, 0, 0);
        }
    }

    // bf16 partial write: C layout col=lane&15=n, row=lq*4+r=o
    int n_A = nA + lr, n_B = nA + 16 + lr;
    unsigned short* ob = outp + ((size_t)(mc * 8 + b) * OC) * HW;
    #pragma unroll
    for (int r = 0; r < 4; ++r) {
        int o0 = lq * 4 + r;
        ob[(size_t)o0 * HW + n_A]        = (unsigned short)f2bf(accA0[r]);
        ob[(size_t)(o0 + 16) * HW + n_A] = (unsigned short)f2bf(accA1[r]);
        ob[(size_t)o0 * HW + n_B]        = (unsigned short)f2bf(accB0[r]);
        ob[(size_t)(o0 + 16) * HW + n_B] = (unsigned short)f2bf(accB1[r]);
    }
}

// ---------------------------------------------------------------------------
// Kernel 5: out = sum_mc bf16 outp[mc] + xs
__global__ __launch_bounds__(256) void k_red(const unsigned short* __restrict__ outp,
                                             const float* __restrict__ xs,
                                             float* __restrict__ out) {
    int i = (blockIdx.x * 256 + threadIdx.x) * 4;
    float4 r = *(const float4*)(xs + i);
    const unsigned short* op = outp + i;
    #pragma unroll
    for (int mc = 0; mc < 8; ++mc) {
        uint2 p = *(const uint2*)(op + (size_t)mc * 1048576);
        r.x += __builtin_bit_cast(float, p.x << 16);
        r.y += __builtin_bit_cast(float, p.x & 0xffff0000u);
        r.z += __builtin_bit_cast(float, p.y << 16);
        r.w += __builtin_bit_cast(float, p.y & 0xffff0000u);
    }
    *(float4*)(out + i) = r;
}

// ---------------------------------------------------------------------------
extern "C" void kernel_launch(void* const* d_in, const int* in_sizes, int n_in,
                              void* d_out, int out_size, void* d_ws, size_t ws_size,
                              hipStream_t stream) {
    const float* x1    = (const float*)d_in[0];
    const float* x2    = (const float*)d_in[1];
    const float* Wq    = (const float*)d_in[2];
    const float* bq    = (const float*)d_in[3];
    const float* Wk    = (const float*)d_in[4];
    const float* bk    = (const float*)d_in[5];
    const float* Wv    = (const float*)d_in[6];
    const float* Wsc   = (const float*)d_in[7];
    const float* gamma = (const float*)d_in[8];
    float* out = (float*)d_out;
    float* ws  = (float*)d_ws;

    float*          wsv  = ws + WSV_OFF;
    unsigned short* qbp  = (unsigned short*)(ws + QB_OFF);
    unsigned short* kbp  = (unsigned short*)(ws + KB_OFF);
    float*          xsp  = ws + XS_OFF;
    float*          v2   = ws + V2_OFF;
    float*          zpp  = ws + ZP_OFF;
    unsigned short* vzb  = (unsigned short*)(ws + VZB_OFF);
    unsigned short* outp = (unsigned short*)(ws + OUTP_OFF);

    k_wcomb<<<8, 256, 0, stream>>>(Wsc, Wv, wsv);
    k_proj<<<512, 256, 0, stream>>>(x1, x2, Wq, bq, Wk, bk, wsv, Wsc,
                                    qbp, kbp, v2, xsp);
    k_stats<<<2048, 256, 0, stream>>>(kbp, qbp, zpp);
    k_zvz<<<128, 256, 0, stream>>>(zpp, v2, gamma, vzb);
    k_attn<<<2048, 256, 0, stream>>>(qbp, kbp, vzb, outp);
    k_red<<<1024, 256, 0, stream>>>(outp, xsp, out);
}